// Round 8
// baseline (94.498 us; speedup 1.0000x reference)
//
#include <hip/hip_runtime.h>
#include <hip/hip_bf16.h>

#define NB 1024
#define NH 256
#define EMB 128
#define TWOD 256
#define HID 256
#define ROWS 128            // history rows per block
#define BPB 2               // blocks per batch element
#define NBLK (NB * BPB)
#define HISTN 100000
#define REGN 1000

typedef __attribute__((ext_vector_type(4))) float f32x4;
typedef __attribute__((ext_vector_type(8))) short bf16x8;

__device__ __forceinline__ unsigned short f2bf(float f) {
  union { float f; unsigned u; } v; v.f = f;
  unsigned u = v.u;
  unsigned r = (u + 0x7fffu + ((u >> 16) & 1u)) >> 16;
  return (unsigned short)r;
}

__device__ __forceinline__ float bf2f(short s) {
  union { unsigned u; float f; } c;
  c.u = ((unsigned)(unsigned short)s) << 16;
  return c.f;
}

__device__ __forceinline__ bf16x8 pack8(f32x4 a, f32x4 b) {
  union { bf16x8 w; unsigned u[4]; } r;
  float2 p;
  union { __hip_bfloat162 h; unsigned u; } c;
  p.x = a[0]; p.y = a[1]; c.h = __float22bfloat162_rn(p); r.u[0] = c.u;
  p.x = a[2]; p.y = a[3]; c.h = __float22bfloat162_rn(p); r.u[1] = c.u;
  p.x = b[0]; p.y = b[1]; c.h = __float22bfloat162_rn(p); r.u[2] = c.u;
  p.x = b[2]; p.y = b[3]; c.h = __float22bfloat162_rn(p); r.u[3] = c.u;
  return r.w;
}

// W1 [d=256][n=256] fp32 -> W1T [n][d] bf16 (B-fragment: n-major, k contiguous)
__global__ __launch_bounds__(256) void prep_w1t(const float* __restrict__ W1,
                                                unsigned short* __restrict__ W1T) {
  const int d = blockIdx.x;
  const int n = threadIdx.x;
  W1T[(size_t)n * TWOD + d] = f2bf(W1[(size_t)d * HID + n]);
}

// E_hist / E_reg fp32 -> bf16 tables (streamed, 8 elems/thread)
__global__ __launch_bounds__(256) void prep_ebf(const float* __restrict__ Eh,
                                                const float* __restrict__ Er,
                                                unsigned short* __restrict__ EBH,
                                                unsigned short* __restrict__ EBR) {
  const long long NE_H = (long long)HISTN * EMB;   // divisible by 8
  const long long NE_R = (long long)REGN * EMB;
  long long i = ((long long)blockIdx.x * 256 + threadIdx.x) * 8;
  if (i >= NE_H + NE_R) return;
  const float* src; unsigned short* dst; long long off;
  if (i < NE_H) { src = Eh; dst = EBH; off = i; }
  else          { src = Er; dst = EBR; off = i - NE_H; }
  f32x4 v0 = *(const f32x4*)(src + off);
  f32x4 v1 = *(const f32x4*)(src + off + 4);
  *(bf16x8*)(dst + off) = pack8(v0, v1);
}

// 2048 blocks (2 per b), 512 threads = 8 waves, 128 rows per block.
// P0: keys + tgt(f32) -> LDS.
// P1: global_load_lds DMA of raw bf16 rows into swizzled panels (zero VGPR).
// P1.5: in-LDS fold: panel *= tgt (bf16), row-dot accumulated for free.
// P2: round-7 GEMM (kk outer, each W1T fragment feeds 16 MFMAs) + epilogue.
// P3: masked exp + partial sums -> ws slots.
__global__ __launch_bounds__(512, 4) void nais_main(
    const int* __restrict__ history, const int* __restrict__ target,
    const int* __restrict__ hregion, const int* __restrict__ tregion,
    const float* __restrict__ E_targ, const float* __restrict__ E_reg,
    const unsigned short* __restrict__ EBH, const unsigned short* __restrict__ EBR,
    const unsigned short* __restrict__ W1T, const float* __restrict__ b1,
    const float* __restrict__ w2,
    float* __restrict__ part_se, float* __restrict__ part_sd)
{
  const int blk = blockIdx.x;
  const int b = blk >> 1;
  const int r0 = (blk & 1) * ROWS;
  const int tid = threadIdx.x;
  const int lane = tid & 63;
  const int wave = tid >> 6;            // 0..7
  const int l15 = lane & 15;
  const int lhi = lane >> 4;

  __shared__ __align__(16) unsigned short A_h[ROWS * EMB];  // 32 KiB, swizzled
  __shared__ __align__(16) unsigned short A_r[ROWS * EMB];  // 32 KiB, swizzled
  __shared__ __align__(16) float tgt_lds[TWOD];
  __shared__ int keys_h[ROWS];
  __shared__ int keys_r[ROWS];
  __shared__ float dot_lds[ROWS];
  __shared__ float score_parts[8][ROWS];

  const int tgt_item = target[b];

  // ---- P0: keys + target vector ----
  if (tid < ROWS) {
    keys_h[tid] = history[b * NH + r0 + tid];
  } else if (tid < 2 * ROWS) {
    keys_r[tid - ROWS] = hregion[b * NH + r0 + (tid - ROWS)];
  } else {
    const int c = tid - 2 * ROWS;       // 0..255
    tgt_lds[c] = (c < EMB) ? E_targ[(size_t)target[b] * EMB + c]
                           : E_reg[(size_t)tregion[b] * EMB + (c - EMB)];
  }
  __syncthreads();

  // ---- P1: DMA gather (linear LDS dest, inverse-swizzled global source) ----
  {
    #pragma unroll
    for (int q = 0; q < 4; ++q) {
      const int quad = wave * 4 + q;            // 0..31, 4 rows each
      const int r = quad * 4 + (lane >> 4);     // row 0..127
      const int g = (lane & 15) ^ (r & 7);      // source granule (involution)
      const int kh = keys_h[r];
      const unsigned short* gh = EBH + (size_t)kh * EMB + g * 8;
      __builtin_amdgcn_global_load_lds(
          (const __attribute__((address_space(1))) void*)gh,
          (__attribute__((address_space(3))) void*)&A_h[quad * 4 * EMB],
          16, 0, 0);
      const int kr = keys_r[r];
      const unsigned short* gr = EBR + (size_t)kr * EMB + g * 8;
      __builtin_amdgcn_global_load_lds(
          (const __attribute__((address_space(1))) void*)gr,
          (__attribute__((address_space(3))) void*)&A_r[quad * 4 * EMB],
          16, 0, 0);
    }
  }
  asm volatile("s_waitcnt vmcnt(0)" ::: "memory");
  __syncthreads();

  // ---- P1.5: fold tgt into panels + row dots. 4 threads/row, 64 elems each ----
  {
    const int row = wave * 16 + (lane >> 2);
    const int seg = lane & 3;                  // k segment of 64
    unsigned short* panel = (seg < 2) ? A_h : A_r;
    const int g0 = (seg & 1) * 8;              // granule base within panel
    float dsum = 0.f;
    #pragma unroll
    for (int j = 0; j < 8; ++j) {
      const int g = (g0 + j) ^ (row & 7);
      bf16x8* ap = (bf16x8*)&panel[row * EMB + g * 8];
      bf16x8 a = *ap;
      const int kg = seg * 64 + j * 8;         // global k of this granule
      f32x4 t0 = *(const f32x4*)&tgt_lds[kg];
      f32x4 t1 = *(const f32x4*)&tgt_lds[kg + 4];
      f32x4 lo, hi;
      #pragma unroll
      for (int e = 0; e < 4; ++e) { lo[e] = bf2f(a[e]); hi[e] = bf2f(a[4 + e]); }
      lo *= t0; hi *= t1;
      dsum += lo[0] + lo[1] + lo[2] + lo[3] + hi[0] + hi[1] + hi[2] + hi[3];
      *ap = pack8(lo, hi);
    }
    dsum += __shfl_xor(dsum, 1);
    dsum += __shfl_xor(dsum, 2);
    if (seg == 0) dot_lds[row] = dsum;
  }
  __syncthreads();

  // ---- P2: GEMM. wave owns cols [wave*32,+32); kk outer, 16 MFMAs per bfr ----
  {
    const int col0 = wave * 32;
    float b1v[2], w2v[2];
    #pragma unroll
    for (int n = 0; n < 2; ++n) {
      const int colh = col0 + n * 16 + l15;
      b1v[n] = b1[colh];
      w2v[n] = w2[colh];
    }

    f32x4 acc[2][4][2];
    #pragma unroll
    for (int c = 0; c < 2; ++c)
      #pragma unroll
      for (int m = 0; m < 4; ++m)
        #pragma unroll
        for (int n = 0; n < 2; ++n)
          acc[c][m][n] = (f32x4){0.f, 0.f, 0.f, 0.f};

    #pragma unroll
    for (int kk = 0; kk < 8; ++kk) {
      const unsigned short* panel = (kk < 4) ? A_h : A_r;
      bf16x8 bfr[2];
      #pragma unroll
      for (int n = 0; n < 2; ++n) {
        const int colh = col0 + n * 16 + l15;
        bfr[n] = *(const bf16x8*)(W1T + (size_t)colh * TWOD + kk * 32 + lhi * 8);
      }
      bf16x8 af[2][4];
      #pragma unroll
      for (int c = 0; c < 2; ++c)
        #pragma unroll
        for (int m = 0; m < 4; ++m) {
          const int row = c * 64 + m * 16 + l15;
          const int gk = ((kk & 3) * 4 + lhi) ^ (row & 7);
          af[c][m] = *(const bf16x8*)&panel[row * EMB + gk * 8];
        }
      __builtin_amdgcn_s_setprio(1);
      #pragma unroll
      for (int c = 0; c < 2; ++c)
        #pragma unroll
        for (int m = 0; m < 4; ++m)
          #pragma unroll
          for (int n = 0; n < 2; ++n)
            acc[c][m][n] = __builtin_amdgcn_mfma_f32_16x16x32_bf16(af[c][m], bfr[n], acc[c][m][n], 0, 0, 0);
      __builtin_amdgcn_s_setprio(0);
    }

    // epilogue: relu + b1, dot w2, 16-lane reduce -> score_parts[wave][row]
    #pragma unroll
    for (int c = 0; c < 2; ++c) {
      #pragma unroll
      for (int m = 0; m < 4; ++m) {
        #pragma unroll
        for (int r = 0; r < 4; ++r) {
          float p = 0.f;
          #pragma unroll
          for (int n = 0; n < 2; ++n) {
            float hv = acc[c][m][n][r] + b1v[n];  // C/D: col=lane&15, row=(lane>>4)*4+r
            hv = hv > 0.f ? hv : 0.f;
            p += hv * w2v[n];
          }
          p += __shfl_xor(p, 1);
          p += __shfl_xor(p, 2);
          p += __shfl_xor(p, 4);
          p += __shfl_xor(p, 8);
          if (l15 == 0) score_parts[wave][c * 64 + m * 16 + lhi * 4 + r] = p;
        }
      }
    }
  }
  __syncthreads();

  // ---- P3: masked exp + partial sums -> per-(block,wave) ws slots ----
  if (wave < 2) {
    const int lrow = wave * 64 + lane;
    float sc = 0.f;
    #pragma unroll
    for (int w = 0; w < 8; ++w) sc += score_parts[w][lrow];
    float e = (keys_h[lrow] != tgt_item) ? expf(sc) : 0.f;
    float ed = e * dot_lds[lrow];
    #pragma unroll
    for (int off = 32; off >= 1; off >>= 1) {
      e += __shfl_xor(e, off);
      ed += __shfl_xor(ed, off);
    }
    if (lane == 0) {
      part_se[blk * 2 + wave] = e;
      part_sd[blk * 2 + wave] = ed;
    }
  }
}

__global__ __launch_bounds__(256) void finalize(const float* __restrict__ part_se,
                                                const float* __restrict__ part_sd,
                                                float* __restrict__ out) {
  const int b = blockIdx.x * 256 + threadIdx.x;
  if (b < NB) {
    float se = 0.f, sd = 0.f;
    #pragma unroll
    for (int i = 0; i < BPB * 2; ++i) {
      se += part_se[b * BPB * 2 + i];
      sd += part_sd[b * BPB * 2 + i];
    }
    const float pred = (se > 0.f) ? (sd / sqrtf(se)) : 0.f;  // denom = sum^0.5
    out[b] = 1.f / (1.f + expf(-pred));
  }
}

extern "C" void kernel_launch(void* const* d_in, const int* in_sizes, int n_in,
                              void* d_out, int out_size, void* d_ws, size_t ws_size,
                              hipStream_t stream) {
  const int* history = (const int*)d_in[0];
  const int* target  = (const int*)d_in[1];
  const int* hregion = (const int*)d_in[2];
  const int* tregion = (const int*)d_in[3];
  const float* E_hist = (const float*)d_in[4];
  const float* E_targ = (const float*)d_in[5];
  const float* E_reg  = (const float*)d_in[6];
  const float* W1 = (const float*)d_in[7];
  const float* b1 = (const float*)d_in[8];
  const float* w2 = (const float*)d_in[9];
  float* out = (float*)d_out;

  char* p = (char*)d_ws;
  unsigned short* W1T = (unsigned short*)p;  p += (size_t)TWOD * HID * 2;        // 128 KB
  unsigned short* EBR = (unsigned short*)p;  p += (size_t)REGN * EMB * 2;        // 256 KB
  float* part_se = (float*)p;                p += (size_t)NBLK * 2 * 4;          // 16 KB
  float* part_sd = (float*)p;                p += (size_t)NBLK * 2 * 4;          // 16 KB
  unsigned short* EBH = (unsigned short*)p;                                      // 25.6 MB

  prep_w1t<<<TWOD, HID, 0, stream>>>(W1, W1T);
  {
    const long long tot8 = ((long long)HISTN * EMB + (long long)REGN * EMB) / 8;
    const int blocks = (int)((tot8 + 255) / 256);
    prep_ebf<<<blocks, 256, 0, stream>>>(E_hist, E_reg, EBH, EBR);
  }
  nais_main<<<NBLK, 512, 0, stream>>>(history, target, hregion, tregion,
                                      E_targ, E_reg, EBH, EBR, W1T, b1, w2,
                                      part_se, part_sd);
  finalize<<<(NB + 255) / 256, 256, 0, stream>>>(part_se, part_sd, out);
}